// Round 1
// baseline (119.294 us; speedup 1.0000x reference)
//
#include <hip/hip_runtime.h>

#define NB 32      // batch
#define NT 2048    // frames
#define ND 1024    // feature dim
#define NS 128     // max segments

// ---------------------------------------------------------------------------
// Kernel A: per-batch boundary scan -> segment start/count, out1, out2
// grid = NB blocks, 256 threads
// ---------------------------------------------------------------------------
__global__ __launch_bounds__(256)
void seg_scan_kernel(const int* __restrict__ in_boundary,  // [NB, NT+1]
                     int* __restrict__ seg_start,          // [NB, NS]
                     int* __restrict__ seg_count,          // [NB, NS]
                     float* __restrict__ out1,             // [NB, NS]
                     float* __restrict__ out2)             // [NB, NT+1]
{
    const int b   = blockIdx.x;
    const int tid = threadIdx.x;              // 256 threads
    const int* bd = in_boundary + (size_t)b * (NT + 1);

    __shared__ int thr_sum[256];
    __shared__ int starts[NS + 1];            // starts[s] for s = 0..128

    for (int s = tid; s <= NS; s += 256) starts[s] = NT;  // default: no segment
    __syncthreads();

    // each thread scans 8 consecutive frames
    const int t0 = tid * 8;
    int v[8];
    int local = 0;
#pragma unroll
    for (int j = 0; j < 8; ++j) {
        int t = t0 + j;
        int bit = (t == 0) ? 1 : bd[t];       // force boundary at frame 0
        v[j] = bit;
        local += bit;
    }
    thr_sum[tid] = local;
    __syncthreads();

    // Hillis-Steele inclusive scan across 256 thread sums
    for (int off = 1; off < 256; off <<= 1) {
        int val = thr_sum[tid];
        int add = (tid >= off) ? thr_sum[tid - off] : 0;
        __syncthreads();
        thr_sum[tid] = val + add;
        __syncthreads();
    }
    const int excl = thr_sum[tid] - local;    // boundaries strictly before t0

    // record segment starts (each segment start is written by exactly one lane)
    int run = excl;
#pragma unroll
    for (int j = 0; j < 8; ++j) {
        run += v[j];
        int seg = run - 1;                    // seg id of frame t0+j
        if (v[j] && seg <= NS) starts[seg] = t0 + j;
    }
    __syncthreads();

    if (tid < NS) {
        int st = starts[tid];
        int c  = starts[tid + 1] - st;        // 0 for non-existent segments
        seg_start[b * NS + tid] = st;
        seg_count[b * NS + tid] = c;
        out1[b * NS + tid] = (c > 0) ? 1.0f : 0.0f;
    }

    // passthrough of raw in_boundary as float
    for (int t = tid; t <= NT; t += 256)
        out2[(size_t)b * (NT + 1) + t] = (float)bd[t];
}

// ---------------------------------------------------------------------------
// Kernel B: segment mean pooling over contiguous frame ranges
// grid = (NS, NB), 256 threads, each thread owns one float4 of D
// ---------------------------------------------------------------------------
__global__ __launch_bounds__(256)
void pool_kernel(const float* __restrict__ x,          // [NB, NT, ND]
                 const int* __restrict__ seg_start,    // [NB, NS]
                 const int* __restrict__ seg_count,    // [NB, NS]
                 float* __restrict__ pooled)           // [NB, NS, ND]
{
    const int s   = blockIdx.x;
    const int b   = blockIdx.y;
    const int tid = threadIdx.x;              // 256 -> ND/4 float4 lanes

    const int st = seg_start[b * NS + s];
    const int c  = seg_count[b * NS + s];

    const float4* xp = (const float4*)(x + (size_t)b * NT * ND);

    float4 acc = make_float4(0.f, 0.f, 0.f, 0.f);
    for (int t = st; t < st + c; ++t) {
        float4 vv = xp[(size_t)t * (ND / 4) + tid];
        acc.x += vv.x; acc.y += vv.y; acc.z += vv.z; acc.w += vv.w;
    }
    const float inv = (c > 0) ? 1.0f / (float)c : 0.0f;
    acc.x *= inv; acc.y *= inv; acc.z *= inv; acc.w *= inv;

    ((float4*)pooled)[((size_t)b * NS + s) * (ND / 4) + tid] = acc;
}

// ---------------------------------------------------------------------------
extern "C" void kernel_launch(void* const* d_in, const int* in_sizes, int n_in,
                              void* d_out, int out_size, void* d_ws, size_t ws_size,
                              hipStream_t stream) {
    const float* x           = (const float*)d_in[0];       // [NB, NT, ND]
    const int*   in_boundary = (const int*)d_in[1];         // [NB, NT+1]

    float* pooled = (float*)d_out;                          // [NB, NS, ND]
    float* out1   = pooled + (size_t)NB * NS * ND;          // [NB, NS]
    float* out2   = out1 + (size_t)NB * NS;                 // [NB, NT+1]

    int* seg_start = (int*)d_ws;                            // [NB, NS]
    int* seg_count = seg_start + NB * NS;                   // [NB, NS]

    seg_scan_kernel<<<NB, 256, 0, stream>>>(in_boundary, seg_start, seg_count,
                                            out1, out2);
    pool_kernel<<<dim3(NS, NB), 256, 0, stream>>>(x, seg_start, seg_count, pooled);
}

// Round 2
// 65.781 us; speedup vs baseline: 1.8135x; 1.8135x over previous
//
#include <hip/hip_runtime.h>

#define NB 32      // batch
#define NT 2048    // frames
#define ND 1024    // feature dim
#define NS 128     // max segments

// ---------------------------------------------------------------------------
// Kernel A: per-batch boundary scan -> segment start/count, out1, out2
// grid = NB blocks, 256 threads
// ---------------------------------------------------------------------------
__global__ __launch_bounds__(256)
void seg_scan_kernel(const int* __restrict__ in_boundary,  // [NB, NT+1]
                     int* __restrict__ seg_start,          // [NB, NS]
                     int* __restrict__ seg_count,          // [NB, NS]
                     float* __restrict__ out1,             // [NB, NS]
                     float* __restrict__ out2)             // [NB, NT+1]
{
    const int b   = blockIdx.x;
    const int tid = threadIdx.x;              // 256 threads
    const int* bd = in_boundary + (size_t)b * (NT + 1);

    __shared__ int thr_sum[256];
    __shared__ int starts[NS + 1];            // starts[s] for s = 0..128

    for (int s = tid; s <= NS; s += 256) starts[s] = NT;  // default: no segment
    __syncthreads();

    // each thread scans 8 consecutive frames
    const int t0 = tid * 8;
    int v[8];
    int local = 0;
#pragma unroll
    for (int j = 0; j < 8; ++j) {
        int t = t0 + j;
        int bit = (t == 0) ? 1 : bd[t];       // force boundary at frame 0
        v[j] = bit;
        local += bit;
    }
    thr_sum[tid] = local;
    __syncthreads();

    // Hillis-Steele inclusive scan across 256 thread sums
    for (int off = 1; off < 256; off <<= 1) {
        int val = thr_sum[tid];
        int add = (tid >= off) ? thr_sum[tid - off] : 0;
        __syncthreads();
        thr_sum[tid] = val + add;
        __syncthreads();
    }
    const int excl = thr_sum[tid] - local;    // boundaries strictly before t0

    // record segment starts (each segment start is written by exactly one lane)
    int run = excl;
#pragma unroll
    for (int j = 0; j < 8; ++j) {
        run += v[j];
        int seg = run - 1;                    // seg id of frame t0+j
        if (v[j] && seg <= NS) starts[seg] = t0 + j;
    }
    __syncthreads();

    if (tid < NS) {
        int st = starts[tid];
        int c  = starts[tid + 1] - st;        // 0 for non-existent segments
        seg_start[b * NS + tid] = st;
        seg_count[b * NS + tid] = c;
        out1[b * NS + tid] = (c > 0) ? 1.0f : 0.0f;
    }

    // passthrough of raw in_boundary as float
    for (int t = tid; t <= NT; t += 256)
        out2[(size_t)b * (NT + 1) + t] = (float)bd[t];
}

// ---------------------------------------------------------------------------
// Kernel B: segment mean pooling, 8-deep unrolled for memory-level parallelism
// grid = (NS, NB), 256 threads, each thread owns one float4 of D
// ---------------------------------------------------------------------------
__global__ __launch_bounds__(256)
void pool_kernel(const float* __restrict__ x,          // [NB, NT, ND]
                 const int* __restrict__ seg_start,    // [NB, NS]
                 const int* __restrict__ seg_count,    // [NB, NS]
                 float* __restrict__ pooled)           // [NB, NS, ND]
{
    const int s   = blockIdx.x;
    const int b   = blockIdx.y;
    const int tid = threadIdx.x;              // 256 -> ND/4 float4 lanes

    const int st = seg_start[b * NS + s];
    const int c  = seg_count[b * NS + s];

    const float4* xp = (const float4*)(x + (size_t)b * NT * ND) + tid;

    float4 a0 = make_float4(0.f,0.f,0.f,0.f);
    float4 a1 = make_float4(0.f,0.f,0.f,0.f);
    float4 a2 = make_float4(0.f,0.f,0.f,0.f);
    float4 a3 = make_float4(0.f,0.f,0.f,0.f);

    const int end = st + c;
    int t = st;

    // 8 independent float4 loads in flight per iteration
    for (; t + 8 <= end; t += 8) {
        float4 v0 = xp[(size_t)(t + 0) * (ND / 4)];
        float4 v1 = xp[(size_t)(t + 1) * (ND / 4)];
        float4 v2 = xp[(size_t)(t + 2) * (ND / 4)];
        float4 v3 = xp[(size_t)(t + 3) * (ND / 4)];
        float4 v4 = xp[(size_t)(t + 4) * (ND / 4)];
        float4 v5 = xp[(size_t)(t + 5) * (ND / 4)];
        float4 v6 = xp[(size_t)(t + 6) * (ND / 4)];
        float4 v7 = xp[(size_t)(t + 7) * (ND / 4)];
        a0.x += v0.x; a0.y += v0.y; a0.z += v0.z; a0.w += v0.w;
        a1.x += v1.x; a1.y += v1.y; a1.z += v1.z; a1.w += v1.w;
        a2.x += v2.x; a2.y += v2.y; a2.z += v2.z; a2.w += v2.w;
        a3.x += v3.x; a3.y += v3.y; a3.z += v3.z; a3.w += v3.w;
        a0.x += v4.x; a0.y += v4.y; a0.z += v4.z; a0.w += v4.w;
        a1.x += v5.x; a1.y += v5.y; a1.z += v5.z; a1.w += v5.w;
        a2.x += v6.x; a2.y += v6.y; a2.z += v6.z; a2.w += v6.w;
        a3.x += v7.x; a3.y += v7.y; a3.z += v7.z; a3.w += v7.w;
    }
    for (; t < end; ++t) {
        float4 v0 = xp[(size_t)t * (ND / 4)];
        a0.x += v0.x; a0.y += v0.y; a0.z += v0.z; a0.w += v0.w;
    }

    a0.x += a1.x + a2.x + a3.x;
    a0.y += a1.y + a2.y + a3.y;
    a0.z += a1.z + a2.z + a3.z;
    a0.w += a1.w + a2.w + a3.w;

    const float inv = (c > 0) ? 1.0f / (float)c : 0.0f;
    a0.x *= inv; a0.y *= inv; a0.z *= inv; a0.w *= inv;

    ((float4*)pooled)[((size_t)b * NS + s) * (ND / 4) + tid] = a0;
}

// ---------------------------------------------------------------------------
extern "C" void kernel_launch(void* const* d_in, const int* in_sizes, int n_in,
                              void* d_out, int out_size, void* d_ws, size_t ws_size,
                              hipStream_t stream) {
    const float* x           = (const float*)d_in[0];       // [NB, NT, ND]
    const int*   in_boundary = (const int*)d_in[1];         // [NB, NT+1]

    float* pooled = (float*)d_out;                          // [NB, NS, ND]
    float* out1   = pooled + (size_t)NB * NS * ND;          // [NB, NS]
    float* out2   = out1 + (size_t)NB * NS;                 // [NB, NT+1]

    int* seg_start = (int*)d_ws;                            // [NB, NS]
    int* seg_count = seg_start + NB * NS;                   // [NB, NS]

    seg_scan_kernel<<<NB, 256, 0, stream>>>(in_boundary, seg_start, seg_count,
                                            out1, out2);
    pool_kernel<<<dim3(NS, NB), 256, 0, stream>>>(x, seg_start, seg_count, pooled);
}